// Round 3
// baseline (185.275 us; speedup 1.0000x reference)
//
#include <hip/hip_runtime.h>
#include <hip/hip_bf16.h>
#include <stdint.h>

typedef float  f32x4  __attribute__((ext_vector_type(4)));
typedef __bf16 bf16x8 __attribute__((ext_vector_type(8)));
typedef unsigned short us4 __attribute__((ext_vector_type(4)));

#define NDIM 4096
#define DDIM 512
#define PSTRIDE 2097152   // elements per split-K partial (512*4096 = 4096*512)
#define NPART 8           // split-K factor for the two big GEMMs (256 blocks = 1/CU)

__device__ __forceinline__ unsigned short f2bf(float f) {
    union { float f; uint32_t u; } v; v.f = f;
    uint32_t u = v.u;
    u += 0x7FFFu + ((u >> 16) & 1u);   // round-to-nearest-even
    return (unsigned short)(u >> 16);
}

__device__ __forceinline__ float b2f(unsigned short s) {
    union { uint32_t u; float f; } v; v.u = (uint32_t)s << 16; return v.f;
}

__device__ __forceinline__ f32x4 us4tof(us4 u) {
    f32x4 r; r.x = b2f(u.x); r.y = b2f(u.y); r.z = b2f(u.z); r.w = b2f(u.w);
    return r;
}

// Fused prep (block-range dispatch):
//   [0, 16384)      : A fp32 -> bf16 with +I      (4096x4096, float4/thread)
//   [16384, 18432)  : X fp32 -> bf16              (4096x512)
//   [18432, 18688)  : W fp32 -> bf16              (512x512)
//   [18688, 18704)  : ds[i] = rsqrt(A[i,i]+1)
__global__ void prep_kernel(const float* __restrict__ A, const float* __restrict__ X,
                            const float* __restrict__ W,
                            unsigned short* __restrict__ A2, unsigned short* __restrict__ Xb,
                            unsigned short* __restrict__ Wb, float* __restrict__ ds) {
    const int b = blockIdx.x, tid = threadIdx.x;
    if (b < 16384) {
        int i = b * 256 + tid;          // float4 index into A
        int e = i << 2;
        int row = e >> 12, col = e & 4095;
        f32x4 v = ((const f32x4*)A)[i];
        int d = row - col;
        if (d >= 0 && d < 4) v[d] += 1.0f;
        us4 o; o.x = f2bf(v.x); o.y = f2bf(v.y); o.z = f2bf(v.z); o.w = f2bf(v.w);
        ((us4*)A2)[i] = o;
    } else if (b < 18432) {
        int i = (b - 16384) * 256 + tid;
        f32x4 v = ((const f32x4*)X)[i];
        us4 o; o.x = f2bf(v.x); o.y = f2bf(v.y); o.z = f2bf(v.z); o.w = f2bf(v.w);
        ((us4*)Xb)[i] = o;
    } else if (b < 18688) {
        int i = (b - 18432) * 256 + tid;
        f32x4 v = ((const f32x4*)W)[i];
        us4 o; o.x = f2bf(v.x); o.y = f2bf(v.y); o.z = f2bf(v.z); o.w = f2bf(v.w);
        ((us4*)Wb)[i] = o;
    } else {
        int i = (b - 18688) * 256 + tid;
        if (i < NDIM) ds[i] = rsqrtf(A[(size_t)i * (NDIM + 1)] + 1.0f);
    }
}

// ---------------------------------------------------------------------------
// Small GEMM (proven path), used only for Yt = (X@W^T)^T.
// C = A @ B^T.  128x128 tile, BK=128, MODE 0: store bf16 TRANSPOSED.
// ---------------------------------------------------------------------------
template <int MODE, int SWAP>
__global__ __launch_bounds__(256, 2) void gemm_bt(
    const unsigned short* __restrict__ A,
    const unsigned short* __restrict__ B,
    void* __restrict__ C,
    int K, int kc, int ldc)
{
    __shared__ unsigned short lsA[128 * 128];
    __shared__ unsigned short lsB[128 * 128];

    const int tid  = threadIdx.x;
    const int wid  = tid >> 6;
    const int lane = tid & 63;
    const int m0 = (SWAP ? blockIdx.y : blockIdx.x) * 128;
    const int n0 = (SWAP ? blockIdx.x : blockIdx.y) * 128;
    const int kbase = blockIdx.z * kc;
    const int wm = (wid & 1) * 64;
    const int wn = (wid >> 1) * 64;
    const int quad = lane >> 4;
    const int c16  = lane & 15;

    const int lr    = lane >> 4;        // row within instr (0..3)
    const int chunk = lane & 15;        // 16B chunk within row
    const int offe = ((chunk ^ lr) * 16);

    f32x4 acc[4][4];
    #pragma unroll
    for (int i = 0; i < 4; i++)
        #pragma unroll
        for (int j = 0; j < 4; j++) acc[i][j] = (f32x4)0.0f;

    const char* gA = (const char*)A + ((size_t)(m0 + wid * 32 + lr) * K) * 2;
    const char* gB = (const char*)B + ((size_t)(n0 + wid * 32 + lr) * K) * 2;
    const size_t rowstep = (size_t)4 * K * 2;

    for (int k0 = kbase; k0 < kbase + kc; k0 += 128) {
        const size_t kb = (size_t)k0 * 2;
        #pragma unroll
        for (int i = 0; i < 8; i++) {
            const size_t src = kb + (size_t)i * rowstep + (size_t)(offe ^ ((i & 1) << 6));
            __builtin_amdgcn_global_load_lds(
                (const __attribute__((address_space(1))) void*)(gA + src),
                (__attribute__((address_space(3))) void*)(&lsA[(wid * 8 + i) * 512]),
                16, 0, 0);
            __builtin_amdgcn_global_load_lds(
                (const __attribute__((address_space(1))) void*)(gB + src),
                (__attribute__((address_space(3))) void*)(&lsB[(wid * 8 + i) * 512]),
                16, 0, 0);
        }
        __syncthreads();

        #pragma unroll
        for (int ks = 0; ks < 4; ks++) {
            bf16x8 bfrag[4], afrag[4];
            #pragma unroll
            for (int nt = 0; nt < 4; nt++) {
                int r = wn + nt * 16 + c16;
                int pc = (quad + ks * 4) ^ (r & 7);
                bfrag[nt] = *(const bf16x8*)((const char*)lsB + r * 256 + pc * 16);
            }
            #pragma unroll
            for (int mt = 0; mt < 4; mt++) {
                int r = wm + mt * 16 + c16;
                int pc = (quad + ks * 4) ^ (r & 7);
                afrag[mt] = *(const bf16x8*)((const char*)lsA + r * 256 + pc * 16);
            }
            #pragma unroll
            for (int mt = 0; mt < 4; mt++)
                #pragma unroll
                for (int nt = 0; nt < 4; nt++)
                    acc[mt][nt] = __builtin_amdgcn_mfma_f32_16x16x32_bf16(
                        afrag[mt], bfrag[nt], acc[mt][nt], 0, 0, 0);
        }
        __syncthreads();
    }

    #pragma unroll
    for (int mt = 0; mt < 4; mt++) {
        const int gm0 = m0 + wm + mt * 16 + quad * 4;
        #pragma unroll
        for (int nt = 0; nt < 4; nt++) {
            const int gn = n0 + wn + nt * 16 + c16;
            f32x4 v = acc[mt][nt];
            if (MODE == 0) {
                us4 o;
                o.x = f2bf(v.x); o.y = f2bf(v.y); o.z = f2bf(v.z); o.w = f2bf(v.w);
                *(us4*)((unsigned short*)C + (size_t)gn * ldc + gm0) = o;
            } else {
                unsigned short* o = (unsigned short*)C + (size_t)blockIdx.z * PSTRIDE
                                  + (size_t)gm0 * ldc + gn;
                o[0]               = f2bf(v.x);
                o[ldc]             = f2bf(v.y);
                o[2 * (size_t)ldc] = f2bf(v.z);
                o[3 * (size_t)ldc] = f2bf(v.w);
            }
        }
    }
}

// ---------------------------------------------------------------------------
// Thin-dim GEMM: block tile spans the ENTIRE thin dimension.
// C_partial[z] = A @ B^T (bf16 in, bf16 partials out at C + z*PSTRIDE).
//   gemm2: BM=512 (full M), BN=128  -> A2 (B-operand) read ONCE total.
//   gemm3: BM=128, BN=512 (full N)  -> A2 (A-operand) read ONCE total.
// BK=32 (rows = 64B): every frag ds_read_b128 covers a contiguous 1KB block
// -> naturally conflict-free, NO swizzle; global_load_lds staging is linear.
// 512 thr = 8 waves (WMxWN), wave-tile 128x64 or 64x128 (acc 128 VGPR).
// Schedule: minimum counted 2-phase — stage(t+1) issued at tile top, compute
// tile t, ONE __syncthreads per K-tile (vmcnt drain sits a full body after
// issue; sources are L2/L3-hot).  Grid (32,1,NPART) = 256 blocks = 1/CU.
// ---------------------------------------------------------------------------
template <int BM, int BN, int WM, int WN>
__global__ __launch_bounds__(512, 2) void gemm_thin(
    const unsigned short* __restrict__ A,   // [Mtot x K] bf16 row-major
    const unsigned short* __restrict__ B,   // [Ntot x K] bf16 row-major
    unsigned short* __restrict__ C,         // partials base
    int K, int kc, int ldc)
{
    constexpr int ABYTES = BM * 64;          // A tile bytes (BM x 32 bf16)
    constexpr int BBYTES = BN * 64;
    constexpr int BUFB   = ABYTES + BBYTES;  // bytes per buffer (40960)
    constexpr int TM = BM / WM / 16;         // m-frags per wave
    constexpr int TN = BN / WN / 16;         // n-frags per wave
    constexpr int IA = BM / 128;             // A stage instrs per wave
    constexpr int IB = BN / 128;

    __shared__ char lds[2 * BUFB];           // 80 KB

    const int tid  = threadIdx.x;
    const int wid  = tid >> 6;               // 0..7
    const int lane = tid & 63;
    const int m0 = (BM == 512) ? 0 : blockIdx.x * BM;
    const int n0 = (BN == 512) ? 0 : blockIdx.x * BN;
    const int kbase = blockIdx.z * kc;

    const int wr = wid / WN, wc = wid % WN;
    const int wm = wr * (TM * 16);
    const int wn = wc * (TN * 16);
    const int quad = lane >> 4;
    const int c16  = lane & 15;

    // staging: one instr = 16 rows x 64B (1KB); lane l -> row l>>2, chunk l&3
    const int srow = lane >> 2, schunk = lane & 3;
    const char* gAl = (const char*)A
        + ((size_t)(m0 + wid * (BM / 8) + srow) * K + kbase) * 2 + schunk * 16;
    const char* gBl = (const char*)B
        + ((size_t)(n0 + wid * (BN / 8) + srow) * K + kbase) * 2 + schunk * 16;
    const size_t rst16 = (size_t)16 * K * 2;     // 16-row step between instrs

    // wave-uniform LDS staging bases (byte offsets within a buffer)
    const int dA = wid * (BM / 8) * 64;
    const int dB = ABYTES + wid * (BN / 8) * 64;

    f32x4 acc[TM][TN];
    #pragma unroll
    for (int i = 0; i < TM; i++)
        #pragma unroll
        for (int j = 0; j < TN; j++) acc[i][j] = (f32x4)0.0f;

    const int T = kc >> 5;   // K-tiles of 32

#define GLB(src, dst) __builtin_amdgcn_global_load_lds( \
    (const __attribute__((address_space(1))) void*)(src), \
    (__attribute__((address_space(3))) void*)(dst), 16, 0, 0)

    // prologue: stage tile 0 into buf 0
    #pragma unroll
    for (int i = 0; i < IA; i++) GLB(gAl + (size_t)i * rst16, lds + dA + i * 1024);
    #pragma unroll
    for (int i = 0; i < IB; i++) GLB(gBl + (size_t)i * rst16, lds + dB + i * 1024);
    __syncthreads();

    int bo = 0;   // compute-buffer byte offset (0 / BUFB)
    for (int t = 0; t < T; ++t) {
        if (t + 1 < T) {                      // stage next tile into other buffer
            const char* sa = gAl + (size_t)(t + 1) * 64;
            const char* sb = gBl + (size_t)(t + 1) * 64;
            const int ob = bo ^ BUFB;
            #pragma unroll
            for (int i = 0; i < IA; i++) GLB(sa + (size_t)i * rst16, lds + ob + dA + i * 1024);
            #pragma unroll
            for (int i = 0; i < IB; i++) GLB(sb + (size_t)i * rst16, lds + ob + dB + i * 1024);
        }
        bf16x8 af[TM], bfr[TN];
        #pragma unroll
        for (int mt = 0; mt < TM; mt++)
            af[mt] = *(const bf16x8*)(lds + bo + (wm + mt * 16 + c16) * 64 + quad * 16);
        #pragma unroll
        for (int nt = 0; nt < TN; nt++)
            bfr[nt] = *(const bf16x8*)(lds + bo + ABYTES + (wn + nt * 16 + c16) * 64 + quad * 16);
        #pragma unroll
        for (int mt = 0; mt < TM; mt++)
            #pragma unroll
            for (int nt = 0; nt < TN; nt++)
                acc[mt][nt] = __builtin_amdgcn_mfma_f32_16x16x32_bf16(
                    af[mt], bfr[nt], acc[mt][nt], 0, 0, 0);
        __syncthreads();
        bo ^= BUFB;
    }
#undef GLB

    // epilogue: C/D layout col = lane&15, row = quad*4 + reg
    unsigned short* Cp = C + (size_t)blockIdx.z * PSTRIDE;
    #pragma unroll
    for (int mt = 0; mt < TM; mt++) {
        const int gm0 = m0 + wm + mt * 16 + quad * 4;
        #pragma unroll
        for (int nt = 0; nt < TN; nt++) {
            const int gn = n0 + wn + nt * 16 + c16;
            f32x4 v = acc[mt][nt];
            unsigned short* o = Cp + (size_t)gm0 * ldc + gn;
            o[0]               = f2bf(v.x);
            o[ldc]             = f2bf(v.y);
            o[2 * (size_t)ldc] = f2bf(v.z);
            o[3 * (size_t)ldc] = f2bf(v.w);
        }
    }
}

// T2[j][i] = bf16(ds[i] * sum_z P[z][j][i]).  P: NPART bf16 partials [512 x 4096].
__global__ void ep2_kernel(const unsigned short* __restrict__ P, const float* __restrict__ ds,
                           unsigned short* __restrict__ T2) {
    int t = blockIdx.x * 256 + threadIdx.x;
    int e = t << 2;
    int i = e & 4095;                  // column index
    f32x4 v = us4tof(((const us4*)P)[t]);
    #pragma unroll
    for (int z = 1; z < NPART; z++)
        v += us4tof(((const us4*)(P + (size_t)z * PSTRIDE))[t]);
    f32x4 d = *(const f32x4*)(ds + i);
    us4 o;
    o.x = f2bf(v.x * d.x); o.y = f2bf(v.y * d.y);
    o.z = f2bf(v.z * d.z); o.w = f2bf(v.w * d.w);
    ((us4*)T2)[t] = o;
}

// out[i][j] = relu(ds[i] * sum_z Q[z][i][j]).  Q: NPART bf16 partials [4096 x 512].
__global__ void ep3_kernel(const unsigned short* __restrict__ Q, const float* __restrict__ ds,
                           float* __restrict__ out) {
    int t = blockIdx.x * 256 + threadIdx.x;
    int e = t << 2;
    int i = e >> 9;                    // row index
    float s = ds[i];
    f32x4 v = us4tof(((const us4*)Q)[t]);
    #pragma unroll
    for (int z = 1; z < NPART; z++)
        v += us4tof(((const us4*)(Q + (size_t)z * PSTRIDE))[t]);
    f32x4 o;
    o.x = fmaxf(v.x * s, 0.0f); o.y = fmaxf(v.y * s, 0.0f);
    o.z = fmaxf(v.z * s, 0.0f); o.w = fmaxf(v.w * s, 0.0f);
    ((f32x4*)out)[t] = o;
}

extern "C" void kernel_launch(void* const* d_in, const int* in_sizes, int n_in,
                              void* d_out, int out_size, void* d_ws, size_t ws_size,
                              hipStream_t stream) {
    const float* X = (const float*)d_in[0];   // [4096 x 512]
    const float* A = (const float*)d_in[1];   // [4096 x 4096]
    const float* W = (const float*)d_in[2];   // [512 x 512]

    char* ws = (char*)d_ws;
    float*          dsc  = (float*)ws;                           // 16 KB
    unsigned short* A2   = (unsigned short*)(ws + 16384);        // 32 MB   bf16 A+I
    unsigned short* Xb   = (unsigned short*)(ws + 33570816u);    // 4 MB
    unsigned short* Wb   = (unsigned short*)(ws + 37765120u);    // 512 KB
    unsigned short* Yt   = (unsigned short*)(ws + 38289408u);    // 4 MB    (X@W^T)^T  [512][4096]
    unsigned short* T2   = (unsigned short*)(ws + 42483712u);    // 4 MB    ds*(A2@Y) transposed [512][4096]
    unsigned short* Part = (unsigned short*)(ws + 46678016u);    // 32 MB   NPART x bf16 split-K partials

    prep_kernel<<<18704, 256, 0, stream>>>(A, X, W, A2, Xb, Wb, dsc);

    // Yt = (Xb @ Wb^T)^T  [512][4096] bf16 (small GEMM, 128^2 path).
    gemm_bt<0, 0><<<dim3(32, 4, 1), 256, 0, stream>>>(Xb, Wb, Yt, 512, 512, 4096);
    // Part[z][512][4096] = Yt @ A2^T.  BM=512 full-M; grid-x = 32 n-tiles; z=8.
    gemm_thin<512, 128, 4, 2><<<dim3(32, 1, NPART), 512, 0, stream>>>(
        Yt, A2, Part, 4096, 4096 / NPART, 4096);
    // T2 = bf16(ds_col * sum_z Part[z]).
    ep2_kernel<<<2048, 256, 0, stream>>>(Part, dsc, T2);
    // Part[z][4096][512] = A2 @ T2^T.  BN=512 full-N; grid-x = 32 m-tiles; z=8.
    gemm_thin<128, 512, 2, 4><<<dim3(32, 1, NPART), 512, 0, stream>>>(
        A2, T2, Part, 4096, 4096 / NPART, 512);
    // out = relu(ds_row * sum_z Part[z])  [4096 x 512] fp32.
    ep3_kernel<<<2048, 256, 0, stream>>>(Part, dsc, (float*)d_out);
}

// Round 4
// 167.303 us; speedup vs baseline: 1.1074x; 1.1074x over previous
//
#include <hip/hip_runtime.h>
#include <hip/hip_bf16.h>
#include <stdint.h>

typedef float  f32x4  __attribute__((ext_vector_type(4)));
typedef __bf16 bf16x8 __attribute__((ext_vector_type(8)));
typedef unsigned short us4 __attribute__((ext_vector_type(4)));

#define NDIM 4096
#define DDIM 512
#define PSTRIDE 2097152   // elements per split-K partial (512*4096 = 4096*512)
#define NPART 4           // split-K factor for the two big GEMMs

__device__ __forceinline__ unsigned short f2bf(float f) {
    union { float f; uint32_t u; } v; v.f = f;
    uint32_t u = v.u;
    u += 0x7FFFu + ((u >> 16) & 1u);   // round-to-nearest-even
    return (unsigned short)(u >> 16);
}

__device__ __forceinline__ float b2f(unsigned short s) {
    union { uint32_t u; float f; } v; v.u = (uint32_t)s << 16; return v.f;
}

__device__ __forceinline__ f32x4 us4tof(us4 u) {
    f32x4 r; r.x = b2f(u.x); r.y = b2f(u.y); r.z = b2f(u.z); r.w = b2f(u.w);
    return r;
}

// Fused prep (block-range dispatch):
//   [0, 16384)      : A fp32 -> bf16 with +I      (4096x4096, float4/thread)
//   [16384, 18432)  : X fp32 -> bf16              (4096x512)
//   [18432, 18688)  : W fp32 -> bf16              (512x512)
//   [18688, 18704)  : ds[i] = rsqrt(A[i,i]+1)
__global__ void prep_kernel(const float* __restrict__ A, const float* __restrict__ X,
                            const float* __restrict__ W,
                            unsigned short* __restrict__ A2, unsigned short* __restrict__ Xb,
                            unsigned short* __restrict__ Wb, float* __restrict__ ds) {
    const int b = blockIdx.x, tid = threadIdx.x;
    if (b < 16384) {
        int i = b * 256 + tid;          // float4 index into A
        int e = i << 2;
        int row = e >> 12, col = e & 4095;
        f32x4 v = ((const f32x4*)A)[i];
        int d = row - col;
        if (d >= 0 && d < 4) v[d] += 1.0f;
        us4 o; o.x = f2bf(v.x); o.y = f2bf(v.y); o.z = f2bf(v.z); o.w = f2bf(v.w);
        ((us4*)A2)[i] = o;
    } else if (b < 18432) {
        int i = (b - 16384) * 256 + tid;
        f32x4 v = ((const f32x4*)X)[i];
        us4 o; o.x = f2bf(v.x); o.y = f2bf(v.y); o.z = f2bf(v.z); o.w = f2bf(v.w);
        ((us4*)Xb)[i] = o;
    } else if (b < 18688) {
        int i = (b - 18432) * 256 + tid;
        f32x4 v = ((const f32x4*)W)[i];
        us4 o; o.x = f2bf(v.x); o.y = f2bf(v.y); o.z = f2bf(v.z); o.w = f2bf(v.w);
        ((us4*)Wb)[i] = o;
    } else {
        int i = (b - 18688) * 256 + tid;
        if (i < NDIM) ds[i] = rsqrtf(A[(size_t)i * (NDIM + 1)] + 1.0f);
    }
}

// C = A @ B^T.  A: [M x K] bf16 row-major, B: [Nr x K] bf16 row-major.
// BM=BN=128, BK=128: 8 iters/block at z=4 -> HALF the barrier drains of BK=64.
// XOR(r&7) swizzle at 16B granularity: LDS row r, logical chunk c lives at
// phys chunk c^(r&7).  Fragment reads hit 8 distinct bank-groups (2-way = free,
// m136); staging coalescing intact (per 16-lane row-segment the XOR key is
// constant, so 4/8-lane groups cover aligned 64/128B segments exactly).
// 4 waves (2x2), wave-tile 64x64 (4x4 MFMAs of 16x16x32).
// Grid: (x, y, z); z = K-chunk of size kc.
//   SWAP=0: x = m-tile, y = n-tile.  SWAP=1: x = n-tile, y = m-tile.
//   grid-x walks the LARGE streamed matrix (XCD pinning: linear id % 8 = x % 8).
// MODE 0: store bf16 TRANSPOSED (C_t[n][m], ldc = M), single k-chunk.
// MODE 2: bf16 stores into partial buffer C + z*PSTRIDE, row-major [M x ldc].
template <int MODE, int SWAP>
__global__ __launch_bounds__(256, 2) void gemm_bt(
    const unsigned short* __restrict__ A,
    const unsigned short* __restrict__ B,
    void* __restrict__ C,
    int K, int kc, int ldc)
{
    // BK=128: rows of 256B, 128 rows per operand = 32 KB each
    __shared__ unsigned short lsA[128 * 128];
    __shared__ unsigned short lsB[128 * 128];

    const int tid  = threadIdx.x;
    const int wid  = tid >> 6;
    const int lane = tid & 63;
    const int m0 = (SWAP ? blockIdx.y : blockIdx.x) * 128;
    const int n0 = (SWAP ? blockIdx.x : blockIdx.y) * 128;
    const int kbase = blockIdx.z * kc;
    const int wm = (wid & 1) * 64;
    const int wn = (wid >> 1) * 64;
    const int quad = lane >> 4;
    const int c16  = lane & 15;

    // staging geometry (BK=128): 16 lanes per 256B row, 4 rows per instr,
    // 8 instrs per wave per operand.  instr i covers LDS rows wid*32+i*4+lr.
    const int lr    = lane >> 4;        // row within instr (0..3)
    const int chunk = lane & 15;        // 16B chunk within row
    // XOR key for LDS row R = wid*32 + i*4 + lr:  R&7 = (i&1)*4 + lr
    const int offe = ((chunk ^ lr) * 16);        // i even: key = lr
    // i odd: key = lr+4 -> offset = offe ^ 64

    f32x4 acc[4][4];
    #pragma unroll
    for (int i = 0; i < 4; i++)
        #pragma unroll
        for (int j = 0; j < 4; j++) acc[i][j] = (f32x4)0.0f;

    // per-lane row base (row = m0 + wid*32 + lr; instr i adds i*4 rows)
    const char* gA = (const char*)A + ((size_t)(m0 + wid * 32 + lr) * K) * 2;
    const char* gB = (const char*)B + ((size_t)(n0 + wid * 32 + lr) * K) * 2;
    const size_t rowstep = (size_t)4 * K * 2;   // 4 rows per instr

    for (int k0 = kbase; k0 < kbase + kc; k0 += 128) {
        const size_t kb = (size_t)k0 * 2;
        #pragma unroll
        for (int i = 0; i < 8; i++) {
            const size_t src = kb + (size_t)i * rowstep + (size_t)(offe ^ ((i & 1) << 6));
            __builtin_amdgcn_global_load_lds(
                (const __attribute__((address_space(1))) void*)(gA + src),
                (__attribute__((address_space(3))) void*)(&lsA[(wid * 8 + i) * 512]),
                16, 0, 0);
            __builtin_amdgcn_global_load_lds(
                (const __attribute__((address_space(1))) void*)(gB + src),
                (__attribute__((address_space(3))) void*)(&lsB[(wid * 8 + i) * 512]),
                16, 0, 0);
        }
        __syncthreads();

        #pragma unroll
        for (int ks = 0; ks < 4; ks++) {
            bf16x8 bfrag[4], afrag[4];
            #pragma unroll
            for (int nt = 0; nt < 4; nt++) {
                int r = wn + nt * 16 + c16;
                int pc = (quad + ks * 4) ^ (r & 7);
                bfrag[nt] = *(const bf16x8*)((const char*)lsB + r * 256 + pc * 16);
            }
            #pragma unroll
            for (int mt = 0; mt < 4; mt++) {
                int r = wm + mt * 16 + c16;
                int pc = (quad + ks * 4) ^ (r & 7);
                afrag[mt] = *(const bf16x8*)((const char*)lsA + r * 256 + pc * 16);
            }
            #pragma unroll
            for (int mt = 0; mt < 4; mt++)
                #pragma unroll
                for (int nt = 0; nt < 4; nt++)
                    acc[mt][nt] = __builtin_amdgcn_mfma_f32_16x16x32_bf16(
                        afrag[mt], bfrag[nt], acc[mt][nt], 0, 0, 0);
        }
        __syncthreads();
    }

    // epilogue.  C/D layout: col = lane&15, row = (lane>>4)*4 + reg
    #pragma unroll
    for (int mt = 0; mt < 4; mt++) {
        const int gm0 = m0 + wm + mt * 16 + quad * 4;   // 4 consecutive rows
        #pragma unroll
        for (int nt = 0; nt < 4; nt++) {
            const int gn = n0 + wn + nt * 16 + c16;
            f32x4 v = acc[mt][nt];
            if (MODE == 0) {
                us4 o;
                o.x = f2bf(v.x); o.y = f2bf(v.y); o.z = f2bf(v.z); o.w = f2bf(v.w);
                *(us4*)((unsigned short*)C + (size_t)gn * ldc + gm0) = o;
            } else {
                unsigned short* o = (unsigned short*)C + (size_t)blockIdx.z * PSTRIDE
                                  + (size_t)gm0 * ldc + gn;
                o[0]               = f2bf(v.x);
                o[ldc]             = f2bf(v.y);
                o[2 * (size_t)ldc] = f2bf(v.z);
                o[3 * (size_t)ldc] = f2bf(v.w);
            }
        }
    }
}

// T2[j][i] = bf16(ds[i] * sum_z P[z][j][i]).  P: NPART bf16 partials [512 x 4096].
__global__ void ep2_kernel(const unsigned short* __restrict__ P, const float* __restrict__ ds,
                           unsigned short* __restrict__ T2) {
    int t = blockIdx.x * 256 + threadIdx.x;
    int e = t << 2;
    int i = e & 4095;                  // column index
    f32x4 v = us4tof(((const us4*)P)[t]);
    #pragma unroll
    for (int z = 1; z < NPART; z++)
        v += us4tof(((const us4*)(P + (size_t)z * PSTRIDE))[t]);
    f32x4 d = *(const f32x4*)(ds + i);
    us4 o;
    o.x = f2bf(v.x * d.x); o.y = f2bf(v.y * d.y);
    o.z = f2bf(v.z * d.z); o.w = f2bf(v.w * d.w);
    ((us4*)T2)[t] = o;
}

// out[i][j] = relu(ds[i] * sum_z Q[z][i][j]).  Q: NPART bf16 partials [4096 x 512].
__global__ void ep3_kernel(const unsigned short* __restrict__ Q, const float* __restrict__ ds,
                           float* __restrict__ out) {
    int t = blockIdx.x * 256 + threadIdx.x;
    int e = t << 2;
    int i = e >> 9;                    // row index
    float s = ds[i];
    f32x4 v = us4tof(((const us4*)Q)[t]);
    #pragma unroll
    for (int z = 1; z < NPART; z++)
        v += us4tof(((const us4*)(Q + (size_t)z * PSTRIDE))[t]);
    f32x4 o;
    o.x = fmaxf(v.x * s, 0.0f); o.y = fmaxf(v.y * s, 0.0f);
    o.z = fmaxf(v.z * s, 0.0f); o.w = fmaxf(v.w * s, 0.0f);
    ((f32x4*)out)[t] = o;
}

extern "C" void kernel_launch(void* const* d_in, const int* in_sizes, int n_in,
                              void* d_out, int out_size, void* d_ws, size_t ws_size,
                              hipStream_t stream) {
    const float* X = (const float*)d_in[0];   // [4096 x 512]
    const float* A = (const float*)d_in[1];   // [4096 x 4096]
    const float* W = (const float*)d_in[2];   // [512 x 512]

    char* ws = (char*)d_ws;
    float*          dsc  = (float*)ws;                           // 16 KB
    unsigned short* A2   = (unsigned short*)(ws + 16384);        // 32 MB   bf16 A+I
    unsigned short* Xb   = (unsigned short*)(ws + 33570816u);    // 4 MB
    unsigned short* Wb   = (unsigned short*)(ws + 37765120u);    // 512 KB
    unsigned short* Yt   = (unsigned short*)(ws + 38289408u);    // 4 MB    (X@W^T)^T  [512][4096]
    unsigned short* T2   = (unsigned short*)(ws + 42483712u);    // 4 MB    ds*(A2@Y) transposed [512][4096]
    unsigned short* Part = (unsigned short*)(ws + 46678016u);    // 16 MB   NPART x bf16 split-K partials

    prep_kernel<<<18704, 256, 0, stream>>>(A, X, W, A2, Xb, Wb, dsc);

    // Yt = (Xb @ Wb^T)^T  [512][4096] bf16.  M=4096 (32 m-tiles = grid-x), N=512 (4 n-tiles).
    gemm_bt<0, 0><<<dim3(32, 4, 1), 256, 0, stream>>>(Xb, Wb, Yt, 512, 512, 4096);
    // Part[z][512][4096] = Yt @ A2^T bf16 partials (M=512: 4 m-tiles=y; N=4096: 32 n-tiles=x; z=4).
    gemm_bt<2, 1><<<dim3(32, 4, NPART), 256, 0, stream>>>(Yt, A2, Part, 4096, 4096 / NPART, 4096);
    // T2 = bf16(ds_col * sum_z Part[z]).
    ep2_kernel<<<2048, 256, 0, stream>>>(Part, dsc, T2);
    // Part[z][4096][512] = A2 @ T2^T bf16 partials (M=4096: 32 m-tiles=x; N=512: 4 n-tiles=y; z=4).
    gemm_bt<2, 0><<<dim3(32, 4, NPART), 256, 0, stream>>>(A2, T2, Part, 4096, 4096 / NPART, 512);
    // out = relu(ds_row * sum_z Part[z])  [4096 x 512] fp32.
    ep3_kernel<<<2048, 256, 0, stream>>>(Part, dsc, (float*)d_out);
}